// Round 3
// baseline (234.042 us; speedup 1.0000x reference)
//
#include <hip/hip_runtime.h>
#include <math.h>

// SSIM (16,3,512,512) fp32, 11x11 separable Gaussian, VALID -> per-batch mean [16].
//
// Register-streaming design, no LDS, no main-loop barriers:
//  - 1 output column per thread; 512-thread block covers all 502 columns.
//  - Waves 0-3 take even columns, waves 4-7 odd columns, so the b64-aligned
//    load window offset is wave-uniform and compile-time (no dynamic indexing).
//  - 4 conv channels {r, d, r^2+d^2, r*d} (SSIM needs e11+e22 only as a sum);
//    11-row register ring = 44 floats.
//  - 255x scaling cancels: C1 = 1e-4, C2 = 9e-4 on [0,1] data.

#define WSZ 11
#define IMG 512
#define OSZ 502
#define NT  512
#define CH_OUT 32
#define NCHUNK 16        // ceil(502/32)
#define NGROUP 4

struct WinArg { float w[WSZ]; };

#define C1V 1.0e-4f
#define C2V 9.0e-4f

__global__ __launch_bounds__(NT) void ssim_stream(
    const float* __restrict__ rawp, const float* __restrict__ dstp,
    float* __restrict__ out, WinArg wa, float inv_n)
{
    const int tid  = threadIdx.x;
    const int lane = tid & 63;
    const int wave = tid >> 6;
    const int pw   = tid >> 8;              // 0: even cols, 1: odd cols (wave-uniform)
    const int ci   = tid & 255;             // column pair index
    const int col  = 2 * ci + pw;           // output column owned by this thread
    const bool active = (ci <= 250) && (col < OSZ);

    const int chunk = blockIdx.x;
    const int img   = blockIdx.y;
    const int o0    = chunk * CH_OUT;
    const int olim  = min(o0 + CH_OUT, OSZ);
    const int rlast = min(o0 + CH_OUT + WSZ - 2, IMG - 1);
    const size_t base = (size_t)img * (size_t)(IMG * IMG) + (size_t)(2 * ci);

    float hs[WSZ][4];                       // ring: [slot][{r,d,rr+dd,rd}]
    float acc = 0.0f;

#pragma unroll 1
    for (int g = 0; g < NGROUP; ++g) {
#pragma unroll
        for (int k = 0; k < WSZ; ++k) {
            const int klin = g * WSZ + k;
            const int row  = o0 + klin;
            if (row <= rlast) {
                float R[12], D[12];
                if (active) {
                    const float2* rp = (const float2*)(rawp + base + (size_t)row * IMG);
                    const float2* dp = (const float2*)(dstp + base + (size_t)row * IMG);
#pragma unroll
                    for (int j = 0; j < 6; ++j) {
                        const float2 rv = rp[j], dv = dp[j];
                        R[2 * j] = rv.x; R[2 * j + 1] = rv.y;
                        D[2 * j] = dv.x; D[2 * j + 1] = dv.y;
                    }
                } else {
#pragma unroll
                    for (int j = 0; j < 12; ++j) { R[j] = 0.f; D[j] = 0.f; }
                }

                float s1 = 0.f, s2 = 0.f, s3 = 0.f, s4 = 0.f;
#define HROW(P)                                                         \
                {                                                       \
                    _Pragma("unroll")                                   \
                    for (int j = 0; j < WSZ; ++j) {                     \
                        const float wj = wa.w[j];                       \
                        const float r = R[(P) + j], d = D[(P) + j];     \
                        s1 = fmaf(wj, r, s1);                           \
                        s2 = fmaf(wj, d, s2);                           \
                        const float sq = fmaf(d, d, r * r);             \
                        s3 = fmaf(wj, sq, s3);                          \
                        s4 = fmaf(wj, r * d, s4);                       \
                    }                                                   \
                }
                if (pw == 0) HROW(0) else HROW(1)
#undef HROW
                hs[k][0] = s1; hs[k][1] = s2; hs[k][2] = s3; hs[k][3] = s4;

                const int o = o0 + klin - (WSZ - 1);
                if (klin >= WSZ - 1 && o < olim && active) {
                    float m1 = 0.f, m2 = 0.f, m3 = 0.f, m4 = 0.f;
#pragma unroll
                    for (int i = 0; i < WSZ; ++i) {
                        const int s = (k + 1 + i) % WSZ;    // static after unroll
                        const float wi = wa.w[i];
                        m1 = fmaf(wi, hs[s][0], m1);
                        m2 = fmaf(wi, hs[s][1], m2);
                        m3 = fmaf(wi, hs[s][2], m3);
                        m4 = fmaf(wi, hs[s][3], m4);
                    }
                    const float q1 = m1 * m1, q2 = m2 * m2, mumu = m1 * m2;
                    const float cov  = m4 - mumu;
                    const float vsum = (m3 - q1) - q2;
                    const float num = (2.0f * mumu + C1V) * (2.0f * cov + C2V);
                    const float den = (q1 + q2 + C1V) * (vsum + C2V);
                    acc += num * __builtin_amdgcn_rcpf(den);
                }
            }
        }
    }

    // ---- block reduction -> one atomicAdd per block ----
#pragma unroll
    for (int off = 32; off > 0; off >>= 1) acc += __shfl_down(acc, off, 64);
    __shared__ float wred[NT / 64];
    if (lane == 0) wred[wave] = acc;
    __syncthreads();
    if (tid == 0) {
        float tot = 0.f;
#pragma unroll
        for (int i = 0; i < NT / 64; ++i) tot += wred[i];
        atomicAdd(out + img / 3, tot * inv_n);
    }
}

extern "C" void kernel_launch(void* const* d_in, const int* in_sizes, int n_in,
                              void* d_out, int out_size, void* d_ws, size_t ws_size,
                              hipStream_t stream) {
    const float* raw = (const float*)d_in[0];
    const float* dst = (const float*)d_in[1];
    float* out = (float*)d_out;

    hipMemsetAsync(out, 0, (size_t)out_size * sizeof(float), stream);

    WinArg wa;
    double g[WSZ], s = 0.0;
    for (int i = 0; i < WSZ; ++i) {
        double ax = (double)i - (double)(WSZ - 1) / 2.0;
        g[i] = exp(-(ax * ax) / (2.0 * 1.5 * 1.5));
        s += g[i];
    }
    for (int i = 0; i < WSZ; ++i) wa.w[i] = (float)(g[i] / s);

    const float inv_n = (float)(1.0 / (3.0 * (double)OSZ * (double)OSZ));

    dim3 grid(NCHUNK, 48);
    ssim_stream<<<grid, NT, 0, stream>>>(raw, dst, out, wa, inv_n);
}

// Round 4
// 92.385 us; speedup vs baseline: 2.5333x; 2.5333x over previous
//
#include <hip/hip_runtime.h>
#include <math.h>

// SSIM (16,3,512,512) fp32, 11x11 separable Gaussian, VALID -> per-batch mean [16].
//
// Round-2 column-streaming structure with measured defects fixed:
//  - LDS rows stored channel-interleaved: float4(r[2c],d[2c],r[2c+1],d[2c+1])
//    -> thread's 12-col window = 6 aligned ds_read_b128, conflict-free.
//  - 4 conv channels {r, d, r^2+d^2, r*d}; register ring = 11 x 4 x 2 = 88 floats,
//    every index compile-time static (full unroll, no branches in HROW).
//  - Reg-staged loads (issue all, then barrier+ds_write_b128) so HBM latency
//    overlaps the previous group's compute.
//  - 255x scaling cancels algebraically: C1 = 1e-4, C2 = 9e-4 on [0,1] data.

#define WSZ 11
#define IMG 512
#define OSZ 502
#define NT  256
#define CH_OUT 32
#define NCHUNK 16        // ceil(502/32)
#define NGROUP 4         // 42 rows = 11+11+11+9

struct WinArg { float w[WSZ]; };

#define C1V 1.0e-4f
#define C2V 9.0e-4f

__global__ __launch_bounds__(NT, 2) void ssim_ring(
    const float* __restrict__ rawp, const float* __restrict__ dstp,
    float* __restrict__ out, WinArg wa, float inv_n)
{
    __shared__ float4 srow[WSZ][IMG / 2];   // 11 * 256 * 16B = 45056 B
    __shared__ float wred[NT / 64];

    const int tid  = threadIdx.x;
    const int lane = tid & 63;
    const int wave = tid >> 6;
    const int chunk = blockIdx.x;
    const int img   = blockIdx.y;
    const int o0    = chunk * CH_OUT;
    const int olim  = min(o0 + CH_OUT, OSZ);
    const int rlast = min(o0 + CH_OUT + WSZ - 2, IMG - 1);
    const size_t base = (size_t)img * (size_t)(IMG * IMG) + (size_t)(2 * tid);
    const bool tval = (2 * tid + 1) < OSZ;   // tid <= 250

    float hs[WSZ][4][2];   // ring: [slot][{r,d,rr+dd,rd}][col]  (static only)
    float acc = 0.0f;

#pragma unroll 1
    for (int g = 0; g < NGROUP; ++g) {
        const int rbase = o0 + g * WSZ;

        // ---- stage: issue all global loads first (overlap prior compute) ----
        float2 Rv[WSZ], Dv[WSZ];
#pragma unroll
        for (int k = 0; k < WSZ; ++k) {
            const int row = rbase + k;
            if (row <= rlast) {                       // block-uniform
                Rv[k] = *(const float2*)(rawp + base + (size_t)row * IMG);
                Dv[k] = *(const float2*)(dstp + base + (size_t)row * IMG);
            }
        }
        __syncthreads();   // prior group's LDS reads complete before overwrite
#pragma unroll
        for (int k = 0; k < WSZ; ++k) {
            const int row = rbase + k;
            if (row <= rlast)
                srow[k][tid] = make_float4(Rv[k].x, Dv[k].x, Rv[k].y, Dv[k].y);
        }
        __syncthreads();

        // ---- consume 11 rows: horizontal -> register ring -> vertical+SSIM ----
#pragma unroll
        for (int k = 0; k < WSZ; ++k) {
            const int klin = g * WSZ + k;
            const int row  = rbase + k;
            if (row <= rlast) {
                float4 q[6];
                if (tval) {
#pragma unroll
                    for (int j = 0; j < 6; ++j) q[j] = srow[k][tid + j];
                } else {
#pragma unroll
                    for (int j = 0; j < 6; ++j) q[j] = make_float4(0.f, 0.f, 0.f, 0.f);
                }
                // element e (0..11): r = e&1 ? q[e>>1].z : q[e>>1].x
                //                    d = e&1 ? q[e>>1].w : q[e>>1].y
                float s1a = 0.f, s2a = 0.f, s3a = 0.f, s4a = 0.f;
                float s1b = 0.f, s2b = 0.f, s3b = 0.f, s4b = 0.f;
#pragma unroll
                for (int j = 0; j < WSZ; ++j) {
                    const float wj = wa.w[j];
                    {   // col a: element j
                        const float r = (j & 1) ? q[j >> 1].z : q[j >> 1].x;
                        const float d = (j & 1) ? q[j >> 1].w : q[j >> 1].y;
                        s1a = fmaf(wj, r, s1a);
                        s2a = fmaf(wj, d, s2a);
                        s3a = fmaf(wj, fmaf(d, d, r * r), s3a);
                        s4a = fmaf(wj, r * d, s4a);
                    }
                    {   // col b: element j+1
                        const int e = j + 1;
                        const float r = (e & 1) ? q[e >> 1].z : q[e >> 1].x;
                        const float d = (e & 1) ? q[e >> 1].w : q[e >> 1].y;
                        s1b = fmaf(wj, r, s1b);
                        s2b = fmaf(wj, d, s2b);
                        s3b = fmaf(wj, fmaf(d, d, r * r), s3b);
                        s4b = fmaf(wj, r * d, s4b);
                    }
                }
                hs[k][0][0] = s1a; hs[k][1][0] = s2a; hs[k][2][0] = s3a; hs[k][3][0] = s4a;
                hs[k][0][1] = s1b; hs[k][1][1] = s2b; hs[k][2][1] = s3b; hs[k][3][1] = s4b;

                const int o = o0 + klin - (WSZ - 1);
                if (klin >= WSZ - 1 && o < olim && tval) {
                    float m1a = 0.f, m2a = 0.f, m3a = 0.f, m4a = 0.f;
                    float m1b = 0.f, m2b = 0.f, m3b = 0.f, m4b = 0.f;
#pragma unroll
                    for (int i = 0; i < WSZ; ++i) {
                        const int s = (k + 1 + i) % WSZ;   // static after unroll
                        const float wi = wa.w[i];
                        m1a = fmaf(wi, hs[s][0][0], m1a);
                        m2a = fmaf(wi, hs[s][1][0], m2a);
                        m3a = fmaf(wi, hs[s][2][0], m3a);
                        m4a = fmaf(wi, hs[s][3][0], m4a);
                        m1b = fmaf(wi, hs[s][0][1], m1b);
                        m2b = fmaf(wi, hs[s][1][1], m2b);
                        m3b = fmaf(wi, hs[s][2][1], m3b);
                        m4b = fmaf(wi, hs[s][3][1], m4b);
                    }
                    {
                        const float q1 = m1a * m1a, q2 = m2a * m2a, mm = m1a * m2a;
                        const float num = (2.f * mm + C1V) * (2.f * (m4a - mm) + C2V);
                        const float den = (q1 + q2 + C1V) * (((m3a - q1) - q2) + C2V);
                        acc += num * __builtin_amdgcn_rcpf(den);
                    }
                    {
                        const float q1 = m1b * m1b, q2 = m2b * m2b, mm = m1b * m2b;
                        const float num = (2.f * mm + C1V) * (2.f * (m4b - mm) + C2V);
                        const float den = (q1 + q2 + C1V) * (((m3b - q1) - q2) + C2V);
                        acc += num * __builtin_amdgcn_rcpf(den);
                    }
                }
            }
        }
    }

    // ---- block reduction -> one atomicAdd per block ----
#pragma unroll
    for (int off = 32; off > 0; off >>= 1) acc += __shfl_down(acc, off, 64);
    if (lane == 0) wred[wave] = acc;
    __syncthreads();
    if (tid == 0) {
        const float tot = (wred[0] + wred[1]) + (wred[2] + wred[3]);
        atomicAdd(out + img / 3, tot * inv_n);
    }
}

extern "C" void kernel_launch(void* const* d_in, const int* in_sizes, int n_in,
                              void* d_out, int out_size, void* d_ws, size_t ws_size,
                              hipStream_t stream) {
    const float* raw = (const float*)d_in[0];
    const float* dst = (const float*)d_in[1];
    float* out = (float*)d_out;

    hipMemsetAsync(out, 0, (size_t)out_size * sizeof(float), stream);

    WinArg wa;
    double g[WSZ], s = 0.0;
    for (int i = 0; i < WSZ; ++i) {
        double ax = (double)i - (double)(WSZ - 1) / 2.0;
        g[i] = exp(-(ax * ax) / (2.0 * 1.5 * 1.5));
        s += g[i];
    }
    for (int i = 0; i < WSZ; ++i) wa.w[i] = (float)(g[i] / s);

    const float inv_n = (float)(1.0 / (3.0 * (double)OSZ * (double)OSZ));

    dim3 grid(NCHUNK, 48);
    ssim_ring<<<grid, NT, 0, stream>>>(raw, dst, out, wa, inv_n);
}

// Round 5
// 85.780 us; speedup vs baseline: 2.7284x; 1.0770x over previous
//
#include <hip/hip_runtime.h>
#include <math.h>

// SSIM (16,3,512,512) fp32, 11x11 separable Gaussian, VALID -> per-batch mean [16].
//
// Round-5: DMA-staged row-streaming pipeline.
//  - 1 output column per thread; blockIdx.z = column parity (even/odd blocks),
//    so every thread reads the SAME aligned float4 window q[tid..tid+5]; only
//    the extraction pattern differs, selected by one block-uniform branch.
//  - LDS = 13-slot circular row buffer, rows stored channel-interleaved
//    float4(r[2m],d[2m],r[2m+1],d[2m+1]), filled by global_load_lds width=4
//    with per-lane source addressing (lane parity -> raw/dst pointer).
//  - Software pipeline: stage row r+2, counted s_waitcnt vmcnt(8) (never 0),
//    raw s_barrier, compute row r. 4-channel register ring {r,d,rr+dd,rd}
//    = 44 floats, all indices compile-time static.
//  - 255x scaling cancels algebraically: C1 = 1e-4, C2 = 9e-4 on [0,1] data.

#define WSZ 11
#define IMG 512
#define OSZ 502
#define NT  256
#define CH_OUT 64
#define NCHUNK 8          // ceil(502/64)
#define NSLOT 13

struct WinArg { float w[WSZ]; };

typedef const __attribute__((address_space(1))) unsigned int* gp_t;
typedef __attribute__((address_space(3))) unsigned int* sp_t;

#define C1V 1.0e-4f
#define C2V 9.0e-4f

__global__ __launch_bounds__(NT, 4) void ssim_dma(
    const float* __restrict__ rawp, const float* __restrict__ dstp,
    float* __restrict__ out, WinArg wa, float inv_n)
{
    __shared__ float4 srow[NSLOT][IMG / 2];   // 13 * 4096 B = 53248 B
    __shared__ float wred[NT / 64];

    const int tid  = threadIdx.x;
    const int lane = tid & 63;
    const int wave = tid >> 6;
    const int chunk = blockIdx.x;
    const int img   = blockIdx.y;
    const int P     = blockIdx.z;            // 0: even output cols, 1: odd

    const int o0    = chunk * CH_OUT;
    const int olim  = min(o0 + CH_OUT, OSZ);
    const int rlast = min(o0 + CH_OUT + WSZ - 2, IMG - 1);
    const int NR    = rlast - o0 + 1;        // rows to stream (74 or 64)

    const size_t ibase = (size_t)img * (size_t)(IMG * IMG);
    // staging: lane covers channel (lane&1), img col wave*128 + n*32 + (lane>>1)
    const float* lane_base = ((lane & 1) ? dstp : rawp) + ibase
                           + (size_t)(wave * 128 + (lane >> 1));
    float* lds_f = (float*)&srow[0][0];

    const bool active = (tid <= 250);        // col = 2*tid + P <= 501
    const int  rtid   = active ? tid : 250;  // clamp LDS window for idle lanes

#define STAGE(ROW, SLOT)                                                      \
    {                                                                         \
        const float* _src = lane_base + (size_t)(ROW) * IMG;                  \
        float* _dst = lds_f + (SLOT) * 1024 + wave * 256;                     \
        __builtin_amdgcn_global_load_lds((gp_t)(const void*)(_src +  0),      \
                                         (sp_t)(void*)(_dst +   0), 4, 0, 0); \
        __builtin_amdgcn_global_load_lds((gp_t)(const void*)(_src + 32),      \
                                         (sp_t)(void*)(_dst +  64), 4, 0, 0); \
        __builtin_amdgcn_global_load_lds((gp_t)(const void*)(_src + 64),      \
                                         (sp_t)(void*)(_dst + 128), 4, 0, 0); \
        __builtin_amdgcn_global_load_lds((gp_t)(const void*)(_src + 96),      \
                                         (sp_t)(void*)(_dst + 192), 4, 0, 0); \
    }

    float hs[WSZ][4];                        // ring: [slot][{r,d,rr+dd,rd}]
    float acc = 0.0f;

    // prologue: rows 0 and 1 in flight
    STAGE(o0 + 0, 0)
    STAGE(o0 + 1, 1)

#pragma unroll 1
    for (int rr = 0; rr < NR; rr += WSZ) {
#pragma unroll
        for (int k = 0; k < WSZ; ++k) {
            const int klin = rr + k;
            if (klin < NR) {                 // block-uniform
                // stage row klin+2 (clamped tail restage keeps vmcnt exact;
                // it lands in a slot that is never read again)
                {
                    int rs = klin + 2; rs = (rs > NR - 1) ? (NR - 1) : rs;
                    const int ss = (klin + 2) % NSLOT;
                    STAGE(o0 + rs, ss)
                }
                asm volatile("s_waitcnt vmcnt(8)" ::: "memory");
                __builtin_amdgcn_s_barrier();
                __builtin_amdgcn_sched_barrier(0);

                const int sc = klin % NSLOT;
                float4 q[6];
                {
                    const float4* rp = &srow[sc][rtid];
#pragma unroll
                    for (int j = 0; j < 6; ++j) q[j] = rp[j];
                }

#define HPASS(PP)                                                              \
                {                                                              \
                    float s1 = 0.f, s2 = 0.f, s3 = 0.f, s4 = 0.f;              \
                    _Pragma("unroll")                                          \
                    for (int j = 0; j < WSZ; ++j) {                            \
                        const float wj = wa.w[j];                              \
                        const int e = (PP) + j;                                \
                        const float r = (e & 1) ? q[e >> 1].z : q[e >> 1].x;   \
                        const float d = (e & 1) ? q[e >> 1].w : q[e >> 1].y;   \
                        s1 = fmaf(wj, r, s1);                                  \
                        s2 = fmaf(wj, d, s2);                                  \
                        s3 = fmaf(wj, fmaf(d, d, r * r), s3);                  \
                        s4 = fmaf(wj, r * d, s4);                              \
                    }                                                          \
                    hs[k][0] = s1; hs[k][1] = s2; hs[k][2] = s3; hs[k][3] = s4;\
                }
                if (P == 0) { HPASS(0) } else { HPASS(1) }
#undef HPASS

                const int o = o0 + klin - (WSZ - 1);
                if (klin >= WSZ - 1 && o < olim && active) {
                    float m1 = 0.f, m2 = 0.f, m3 = 0.f, m4 = 0.f;
#pragma unroll
                    for (int i = 0; i < WSZ; ++i) {
                        const int s = (k + 1 + i) % WSZ;   // static after unroll
                        const float wi = wa.w[i];
                        m1 = fmaf(wi, hs[s][0], m1);
                        m2 = fmaf(wi, hs[s][1], m2);
                        m3 = fmaf(wi, hs[s][2], m3);
                        m4 = fmaf(wi, hs[s][3], m4);
                    }
                    const float q1 = m1 * m1, q2 = m2 * m2, mm = m1 * m2;
                    const float num = (2.f * mm + C1V) * (2.f * (m4 - mm) + C2V);
                    const float den = (q1 + q2 + C1V) * (((m3 - q1) - q2) + C2V);
                    acc += num * __builtin_amdgcn_rcpf(den);
                }
            }
        }
    }
#undef STAGE

    // ---- block reduction -> one atomicAdd per block ----
#pragma unroll
    for (int off = 32; off > 0; off >>= 1) acc += __shfl_down(acc, off, 64);
    if (lane == 0) wred[wave] = acc;
    __syncthreads();
    if (tid == 0) {
        const float tot = (wred[0] + wred[1]) + (wred[2] + wred[3]);
        atomicAdd(out + img / 3, tot * inv_n);
    }
}

extern "C" void kernel_launch(void* const* d_in, const int* in_sizes, int n_in,
                              void* d_out, int out_size, void* d_ws, size_t ws_size,
                              hipStream_t stream) {
    const float* raw = (const float*)d_in[0];
    const float* dst = (const float*)d_in[1];
    float* out = (float*)d_out;

    hipMemsetAsync(out, 0, (size_t)out_size * sizeof(float), stream);

    WinArg wa;
    double g[WSZ], s = 0.0;
    for (int i = 0; i < WSZ; ++i) {
        double ax = (double)i - (double)(WSZ - 1) / 2.0;
        g[i] = exp(-(ax * ax) / (2.0 * 1.5 * 1.5));
        s += g[i];
    }
    for (int i = 0; i < WSZ; ++i) wa.w[i] = (float)(g[i] / s);

    const float inv_n = (float)(1.0 / (3.0 * (double)OSZ * (double)OSZ));

    dim3 grid(NCHUNK, 48, 2);
    ssim_dma<<<grid, NT, 0, stream>>>(raw, dst, out, wa, inv_n);
}

// Round 6
// 78.649 us; speedup vs baseline: 2.9758x; 1.0907x over previous
//
#include <hip/hip_runtime.h>
#include <math.h>

// SSIM (16,3,512,512) fp32, 11x11 separable Gaussian, VALID -> per-batch mean [16].
//
// Round-6: barrier-free per-wave streaming.
//  - Each wave owns a 128-output-col strip (2 cols/thread) and stages its own
//    160-col (incl. halo) input rows via global_load_lds -> per-wave vmcnt is
//    the ONLY synchronization; no s_barrier in the main loop.
//  - LDS: per-wave 11-slot row ring, channel-interleaved float4(r,d,r,d);
//    waves 0-2: 5 chunks/row (80 float4/slot), wave 3: 4 chunks (64 float4).
//  - Lookahead 6 rows, counted s_waitcnt vmcnt(24) (never drained to 0).
//  - 4-channel register ring {r,d,rr+dd,rd} x 2 cols = 88 floats, all indices
//    compile-time static (slot = k, NSLOT = 11 = unroll factor).
//  - 255x scaling cancels algebraically: C1 = 1e-4, C2 = 9e-4 on [0,1] data.

#define WSZ 11
#define IMG 512
#define OSZ 502
#define NT  256
#define CH_OUT 32
#define NCHUNK 16        // 16*32 >= 502
#define NSLOT 11
#define LA 6             // lookahead rows

struct WinArg { float w[WSZ]; };

typedef const __attribute__((address_space(1))) unsigned int* gp_t;
typedef __attribute__((address_space(3))) unsigned int* sp_t;

#define C1V 1.0e-4f
#define C2V 9.0e-4f

__global__ __launch_bounds__(NT, 3) void ssim_wavestream(
    const float* __restrict__ rawp, const float* __restrict__ dstp,
    float* __restrict__ out, WinArg wa, float inv_n)
{
    // waves 0-2: 11 slots x 80 float4 (880 f4 each); wave 3: 11 x 64 (704 f4)
    __shared__ float4 srow[3344];            // 53504 B -> 3 blocks/CU
    __shared__ float wred[NT / 64];

    const int tid  = threadIdx.x;
    const int lane = tid & 63;
    const int wave = tid >> 6;
    const int chunk = blockIdx.x;
    const int img   = blockIdx.y;

    const int o0    = chunk * CH_OUT;
    const int olim  = min(o0 + CH_OUT, OSZ);
    const int rlast = min(o0 + CH_OUT + WSZ - 2, IMG - 1);
    const int NR    = rlast - o0 + 1;        // 42 (32 for last chunk)

    const bool w3     = (wave == 3);
    const int  nch    = w3 ? 4 : 5;          // DMA chunks per row (wave-uniform)
    const int  slotf4 = w3 ? 64 : 80;        // float4 per slot (wave-uniform)
    float4* region = srow + wave * 880;      // wave 3 -> 2640, uses 704 f4
    const int  rl     = (w3 && lane > 58) ? 58 : lane;   // read clamp (broadcast)
    const bool active = !(w3 && lane > 58);  // cols 2*(128w/2+lane)+{0,1} valid

    const size_t ibase = (size_t)img * (size_t)(IMG * IMG);
    // lane parity -> channel; (lane>>1) -> col within 32-col chunk
    const float* lane_base = ((lane & 1) ? dstp : rawp) + ibase
                           + (size_t)(wave * 128 + (lane >> 1));

#define STAGE(ROW, SLOT)                                                       \
    {                                                                          \
        const float* _s = lane_base + (size_t)(ROW) * IMG;                     \
        float* _d = (float*)(region + (SLOT) * slotf4);                        \
        _Pragma("unroll")                                                      \
        for (int _c = 0; _c < 5; ++_c) {                                       \
            if (_c < nch)                                                      \
                __builtin_amdgcn_global_load_lds(                              \
                    (gp_t)(const void*)(_s + 32 * _c),                         \
                    (sp_t)(void*)(_d + 64 * _c), 4, 0, 0);                     \
        }                                                                      \
    }

    float hs[WSZ][4][2];                     // ring: [slot][{r,d,rr+dd,rd}][col]
    float acc = 0.0f;

    // prologue: rows 0..LA-1 in flight (slots 0..5)
#pragma unroll
    for (int r = 0; r < LA; ++r) STAGE(o0 + r, r)

#pragma unroll 1
    for (int rr = 0; rr < NR; rr += WSZ) {
#pragma unroll
        for (int k = 0; k < WSZ; ++k) {
            const int klin = rr + k;
            if (klin < NR) {                 // block-uniform
                // stage row klin+LA (clamped tail restage lands in unused slot)
                {
                    int rs = klin + LA; if (rs > NR - 1) rs = NR - 1;
                    STAGE(o0 + rs, (k + LA) % NSLOT)
                }
                // per-wave wait: guarantees row klin's loads complete
                // (waves 0-2: >=11 oldest of <=35 drained; wave 3: >=4 of <=28)
                asm volatile("s_waitcnt vmcnt(24)" ::: "memory");

                float4 q[6];
                {
                    const float4* rp = region + k * slotf4 + rl;
#pragma unroll
                    for (int j = 0; j < 6; ++j) q[j] = rp[j];
                }

                // ---- horizontal pass, 2 cols (elements 0..10 and 1..11) ----
                float s1a = 0.f, s2a = 0.f, s3a = 0.f, s4a = 0.f;
                float s1b = 0.f, s2b = 0.f, s3b = 0.f, s4b = 0.f;
#pragma unroll
                for (int j = 0; j < WSZ; ++j) {
                    const float wj = wa.w[j];
                    {   // col a: element j
                        const float r = (j & 1) ? q[j >> 1].z : q[j >> 1].x;
                        const float d = (j & 1) ? q[j >> 1].w : q[j >> 1].y;
                        s1a = fmaf(wj, r, s1a);
                        s2a = fmaf(wj, d, s2a);
                        s3a = fmaf(wj, fmaf(d, d, r * r), s3a);
                        s4a = fmaf(wj, r * d, s4a);
                    }
                    {   // col b: element j+1
                        const int e = j + 1;
                        const float r = (e & 1) ? q[e >> 1].z : q[e >> 1].x;
                        const float d = (e & 1) ? q[e >> 1].w : q[e >> 1].y;
                        s1b = fmaf(wj, r, s1b);
                        s2b = fmaf(wj, d, s2b);
                        s3b = fmaf(wj, fmaf(d, d, r * r), s3b);
                        s4b = fmaf(wj, r * d, s4b);
                    }
                }
                hs[k][0][0] = s1a; hs[k][1][0] = s2a; hs[k][2][0] = s3a; hs[k][3][0] = s4a;
                hs[k][0][1] = s1b; hs[k][1][1] = s2b; hs[k][2][1] = s3b; hs[k][3][1] = s4b;

                // ---- vertical pass + SSIM ----
                const int o = o0 + klin - (WSZ - 1);
                if (klin >= WSZ - 1 && o < olim && active) {
                    float m1a = 0.f, m2a = 0.f, m3a = 0.f, m4a = 0.f;
                    float m1b = 0.f, m2b = 0.f, m3b = 0.f, m4b = 0.f;
#pragma unroll
                    for (int i = 0; i < WSZ; ++i) {
                        const int s = (k + 1 + i) % WSZ;   // static after unroll
                        const float wi = wa.w[i];
                        m1a = fmaf(wi, hs[s][0][0], m1a);
                        m2a = fmaf(wi, hs[s][1][0], m2a);
                        m3a = fmaf(wi, hs[s][2][0], m3a);
                        m4a = fmaf(wi, hs[s][3][0], m4a);
                        m1b = fmaf(wi, hs[s][0][1], m1b);
                        m2b = fmaf(wi, hs[s][1][1], m2b);
                        m3b = fmaf(wi, hs[s][2][1], m3b);
                        m4b = fmaf(wi, hs[s][3][1], m4b);
                    }
                    {
                        const float q1 = m1a * m1a, q2 = m2a * m2a, mm = m1a * m2a;
                        const float num = (2.f * mm + C1V) * (2.f * (m4a - mm) + C2V);
                        const float den = (q1 + q2 + C1V) * (((m3a - q1) - q2) + C2V);
                        acc += num * __builtin_amdgcn_rcpf(den);
                    }
                    {
                        const float q1 = m1b * m1b, q2 = m2b * m2b, mm = m1b * m2b;
                        const float num = (2.f * mm + C1V) * (2.f * (m4b - mm) + C2V);
                        const float den = (q1 + q2 + C1V) * (((m3b - q1) - q2) + C2V);
                        acc += num * __builtin_amdgcn_rcpf(den);
                    }
                }
            }
        }
    }
#undef STAGE

    // ---- block reduction -> one atomicAdd per block ----
#pragma unroll
    for (int off = 32; off > 0; off >>= 1) acc += __shfl_down(acc, off, 64);
    if (lane == 0) wred[wave] = acc;
    __syncthreads();
    if (tid == 0) {
        const float tot = (wred[0] + wred[1]) + (wred[2] + wred[3]);
        atomicAdd(out + img / 3, tot * inv_n);
    }
}

extern "C" void kernel_launch(void* const* d_in, const int* in_sizes, int n_in,
                              void* d_out, int out_size, void* d_ws, size_t ws_size,
                              hipStream_t stream) {
    const float* raw = (const float*)d_in[0];
    const float* dst = (const float*)d_in[1];
    float* out = (float*)d_out;

    hipMemsetAsync(out, 0, (size_t)out_size * sizeof(float), stream);

    WinArg wa;
    double g[WSZ], s = 0.0;
    for (int i = 0; i < WSZ; ++i) {
        double ax = (double)i - (double)(WSZ - 1) / 2.0;
        g[i] = exp(-(ax * ax) / (2.0 * 1.5 * 1.5));
        s += g[i];
    }
    for (int i = 0; i < WSZ; ++i) wa.w[i] = (float)(g[i] / s);

    const float inv_n = (float)(1.0 / (3.0 * (double)OSZ * (double)OSZ));

    dim3 grid(NCHUNK, 48);
    ssim_wavestream<<<grid, NT, 0, stream>>>(raw, dst, out, wa, inv_n);
}